// Round 1
// baseline (368.229 us; speedup 1.0000x reference)
//
#include <hip/hip_runtime.h>
#include <hip/hip_bf16.h>

#define NA   65536
#define DIN  512
#define DOUT 512
#define NE   8
#define NS   64
#define CAP  2048   // padded per-system perm capacity (mean 1024, sd ~32)
#define BM   128
#define BN   128
#define BK   32

typedef __attribute__((ext_vector_type(8))) __bf16 bf16x8;
typedef __attribute__((ext_vector_type(4))) __bf16 bf16x4;
typedef __attribute__((ext_vector_type(4))) float floatx4;

__device__ __forceinline__ void async_load16(const void* g, void* l) {
  __builtin_amdgcn_global_load_lds(
      (__attribute__((address_space(1))) void*)(void*)g,
      (__attribute__((address_space(3))) void*)l,
      16, 0, 0);
}

__global__ void init_kernel(int* cursors) {
  int t = threadIdx.x;
  if (t < NS) cursors[t] = t * CAP;
}

// Bucket atoms by system: LDS histogram then one global atomic per (block, s).
__global__ void scatter_kernel(const int* __restrict__ bidx,
                               int* __restrict__ cursors,
                               int* __restrict__ perm) {
  __shared__ int hist[NS];
  __shared__ int base[NS];
  int t = threadIdx.x;
  if (t < NS) hist[t] = 0;
  __syncthreads();
  int n = blockIdx.x * 256 + t;
  int s = bidx[n];
  int rank = atomicAdd(&hist[s], 1);
  __syncthreads();
  if (t < NS && hist[t] > 0) base[t] = atomicAdd(&cursors[t], hist[t]);
  __syncthreads();
  perm[base[s] + rank] = n;
}

// mixedW[s][o][i] = sum_e coeff[s][e] * W[e][o][i], stored bf16, K(i)-contiguous.
// Each block caches a 2048-elem chunk of all 8 experts in registers, reuses
// across 32 systems -> W read once from HBM.
__global__ void mixw_kernel(const float* __restrict__ W,
                            const float* __restrict__ coeff,
                            ushort* __restrict__ mixedW) {
  int t = threadIdx.x;
  int base = blockIdx.x * 2048 + t * 8;
  float w[NE][8];
#pragma unroll
  for (int e = 0; e < NE; e++) {
    const float4* p = (const float4*)(W + e * (DOUT * DIN) + base);
    float4 a = p[0], b = p[1];
    w[e][0] = a.x; w[e][1] = a.y; w[e][2] = a.z; w[e][3] = a.w;
    w[e][4] = b.x; w[e][5] = b.y; w[e][6] = b.z; w[e][7] = b.w;
  }
  int s0 = blockIdx.y * 32;
  for (int si = 0; si < 32; si++) {
    int s = s0 + si;
    float o[8] = {0, 0, 0, 0, 0, 0, 0, 0};
#pragma unroll
    for (int e = 0; e < NE; e++) {
      float c = coeff[s * NE + e];  // wave-uniform scalar load
#pragma unroll
      for (int j = 0; j < 8; j++) o[j] += c * w[e][j];
    }
    union { bf16x8 v; uint4 u; } cv;
#pragma unroll
    for (int j = 0; j < 8; j++) cv.v[j] = (__bf16)o[j];
    *(uint4*)(mixedW + (size_t)s * (DOUT * DIN) + base) = cv.u;
  }
}

// Grouped GEMM: out[perm[r]][o] = sum_i x[perm[r]][i] * mixedW[s][o][i] + bias[o]
// 128x128 tile, BK=32, 4 waves (2x2), each wave 4x4 of 16x16x32 bf16 MFMA.
// B staged via global_load_lds (bf16, K-major). A staged fp32->bf16 via VGPRs.
__global__ __launch_bounds__(256) void gemm_kernel(
    const float* __restrict__ x, const ushort* __restrict__ mixedW,
    const int* __restrict__ perm, const int* __restrict__ cursors,
    const float* __restrict__ bias, float* __restrict__ out) {
  int st = blockIdx.y;          // 0..1023 = system*16 + rowtile
  int s = st >> 4;
  int tt = st & 15;
  int count = cursors[s] - s * CAP;
  int r0 = tt * BM;
  if (r0 >= count) return;      // dead tile
  int rows = min(BM, count - r0);
  int n0 = blockIdx.x * BN;

  __shared__ __align__(16) ushort Alds[BM * BK];  // 8KB, [row][k] bf16
  __shared__ __align__(16) ushort Blds[BN * BK];  // 8KB, [o][k]  bf16
  __shared__ int prow[BM];

  int tid = threadIdx.x;
  int lane = tid & 63;
  int wave = tid >> 6;

  if (tid < BM) prow[tid] = perm[s * CAP + r0 + min(tid, rows - 1)];
  __syncthreads();

  // A staging map: thread t loads 4x float4; chunk = 16B piece of a 128B row
  int chunk = tid & 7;
  const float* aptr[4];
#pragma unroll
  for (int q = 0; q < 4; q++) {
    int row = q * 32 + (tid >> 3);
    aptr[q] = x + (size_t)prow[row] * DIN + chunk * 4;
  }
  // B staging map: per wave-load j, lane covers row=(j*4+wave)*16+lane/4,
  // k-bytes (lane&3)*16 -> LDS flat = region*1024 + lane*16 (wave-uniform base)
  const ushort* bptr[2];
  ushort* bl[2];
#pragma unroll
  for (int j = 0; j < 2; j++) {
    int region = j * 4 + wave;
    int row = region * 16 + (lane >> 2);
    bptr[j] = mixedW + (size_t)s * (DOUT * DIN) + (size_t)(n0 + row) * DIN +
              (lane & 3) * 8;
    bl[j] = Blds + region * 512;
  }

  floatx4 acc[4][4];
#pragma unroll
  for (int mt = 0; mt < 4; mt++)
#pragma unroll
    for (int nt = 0; nt < 4; nt++) acc[mt][nt] = {0.f, 0.f, 0.f, 0.f};

  int wm = wave >> 1, wn = wave & 1;
  int m15 = lane & 15, quad = lane >> 4;

  for (int kk = 0; kk < DIN; kk += BK) {
#pragma unroll
    for (int j = 0; j < 2; j++) async_load16(bptr[j] + kk, bl[j]);
#pragma unroll
    for (int q = 0; q < 4; q++) {
      float4 v = *(const float4*)(aptr[q] + kk);
      bf16x4 h;
      h[0] = (__bf16)v.x; h[1] = (__bf16)v.y;
      h[2] = (__bf16)v.z; h[3] = (__bf16)v.w;
      int row = q * 32 + (tid >> 3);
      *(bf16x4*)(Alds + row * BK + chunk * 4) = h;
    }
    __syncthreads();
    bf16x8 af[4], bfm[4];
#pragma unroll
    for (int i = 0; i < 4; i++) {
      af[i]  = *(const bf16x8*)(Alds + (wm * 64 + i * 16 + m15) * BK + quad * 8);
      bfm[i] = *(const bf16x8*)(Blds + (wn * 64 + i * 16 + m15) * BK + quad * 8);
    }
#pragma unroll
    for (int mt = 0; mt < 4; mt++)
#pragma unroll
      for (int nt = 0; nt < 4; nt++)
        acc[mt][nt] = __builtin_amdgcn_mfma_f32_16x16x32_bf16(
            af[mt], bfm[nt], acc[mt][nt], 0, 0, 0);
    __syncthreads();
  }

  // Epilogue: C/D layout col=lane&15 (o), row=quad*4+reg (x-row in tile)
  float bv[4];
#pragma unroll
  for (int nt = 0; nt < 4; nt++) bv[nt] = bias[n0 + wn * 64 + nt * 16 + m15];

#pragma unroll
  for (int mt = 0; mt < 4; mt++) {
    int rb = wm * 64 + mt * 16 + quad * 4;
    int pr[4];
#pragma unroll
    for (int r = 0; r < 4; r++) pr[r] = prow[rb + r];
#pragma unroll
    for (int nt = 0; nt < 4; nt++) {
      int col = n0 + wn * 64 + nt * 16 + m15;
#pragma unroll
      for (int r = 0; r < 4; r++) {
        if (rb + r < rows)
          out[(size_t)pr[r] * DOUT + col] = acc[mt][nt][r] + bv[nt];
      }
    }
  }
}

extern "C" void kernel_launch(void* const* d_in, const int* in_sizes, int n_in,
                              void* d_out, int out_size, void* d_ws,
                              size_t ws_size, hipStream_t stream) {
  const float* x     = (const float*)d_in[0];
  const float* coeff = (const float*)d_in[1];
  const int*   bidx  = (const int*)d_in[2];
  const float* W     = (const float*)d_in[3];
  const float* bias  = (const float*)d_in[4];
  float* out = (float*)d_out;

  char* ws = (char*)d_ws;
  int* cursors   = (int*)ws;                                   // 64 ints
  int* perm      = (int*)(ws + 1024);                          // 512 KB
  ushort* mixedW = (ushort*)(ws + 1024 + CAP * NS * sizeof(int));  // 33.5 MB

  hipLaunchKernelGGL(init_kernel, dim3(1), dim3(64), 0, stream, cursors);
  hipLaunchKernelGGL(scatter_kernel, dim3(NA / 256), dim3(256), 0, stream,
                     bidx, cursors, perm);
  hipLaunchKernelGGL(mixw_kernel, dim3(DOUT * DIN / 2048, 2), dim3(256), 0,
                     stream, W, coeff, mixedW);
  hipLaunchKernelGGL(gemm_kernel, dim3(DOUT / BN, NS * 16), dim3(256), 0,
                     stream, x, mixedW, perm, cursors, bias, out);
}